// Round 5
// baseline (211.613 us; speedup 1.0000x reference)
//
#include <hip/hip_runtime.h>
#include <hip/hip_bf16.h>
#include <math.h>

// Problem constants
#define Bn   2
#define Nn   2048
#define Kn   48
#define Cn   128
#define G2   16     // nodes per block in the tail kernel

typedef short bf16x8 __attribute__((ext_vector_type(8)));
typedef float f32x4  __attribute__((ext_vector_type(4)));

#if __has_builtin(__builtin_amdgcn_cvt_pk_bf16_f32)
#define HAS_PK 1
#endif

__device__ __forceinline__ short f2bf(float f) {
  union { float f; unsigned u; } v; v.f = f;
  unsigned r = v.u + 0x7fffu + ((v.u >> 16) & 1u);
  return (short)(r >> 16);
}

__device__ __forceinline__ unsigned pk2(float a, float b) {
#ifdef HAS_PK
  auto p = __builtin_amdgcn_cvt_pk_bf16_f32(a, b);
  return __builtin_bit_cast(unsigned, p);
#else
  return (unsigned)(unsigned short)f2bf(a) | ((unsigned)(unsigned short)f2bf(b) << 16);
#endif
}

// tanh-GELU with exp2-folded constants; |err| vs erf-gelu ~3e-4.
__device__ __forceinline__ float gelu_f(float x) {
  float z = x * (-2.3021991f - 0.10294200f * x * x);
  float e = __builtin_amdgcn_exp2f(z);
  return x * __builtin_amdgcn_rcpf(1.0f + e);
}

// ---------------------------------------------------------------------------
// Pack weights into bf16 MFMA B-fragment tiles (512 shorts each; lane l holds
// 8 bf16 = W[kt*32 + (l>>4)*8 + j][nt*16 + (l&15)]).
// ws (shorts): W1i [0,16384) | W1e [16384,49152) | W2 [49152,65536)
//              W3 [65536,81920) | Wu [81920,98304)
// ---------------------------------------------------------------------------
__global__ void pack_weights(const float* __restrict__ W1,
                             const float* __restrict__ W2,
                             const float* __restrict__ W3,
                             const float* __restrict__ Wu,
                             short* __restrict__ ws) {
  int tid = blockIdx.x * blockDim.x + threadIdx.x;
  if (tid >= 192 * 64) return;
  int lane = tid & 63;
  int tile = tid >> 6;
  const float* W; short* dst;
  if (tile < 32)       { W = W1;         dst = ws; }
  else if (tile < 96)  { W = W1 + 16384; dst = ws + 16384; tile -= 32; }
  else if (tile < 128) { W = W2;         dst = ws + 49152; tile -= 96; }
  else if (tile < 160) { W = W3;         dst = ws + 65536; tile -= 128; }
  else                 { W = Wu;         dst = ws + 81920; tile -= 160; }
  int kt = tile >> 3, nt = tile & 7;
  int n  = nt * 16 + (lane & 15);
  int k0 = kt * 32 + (lane >> 4) * 8;
  union { short s[8]; bf16x8 v; } u8;
#pragma unroll
  for (int j = 0; j < 8; j++) u8.s[j] = f2bf(W[(k0 + j) * 128 + n]);
  *reinterpret_cast<bf16x8*>(dst + (tile << 9) + lane * 8) = u8.v;
}

// ---------------------------------------------------------------------------
// Kernel 1: per-node edge MLP. One block per node; 256 thr = 4 waves; wave w
// owns cols [w*32,w*32+32). B-fragments live in registers (preloaded);
// GEMM loops touch only LDS (A) + MFMA. 3 barriers.
// Ends writing hs[node][128] (f32 col-sums of gelu(h2)) into the out buffer.
// ---------------------------------------------------------------------------
__global__ __launch_bounds__(256, 4)
void node_update_kernel(const float* __restrict__ node_h,
                        const float* __restrict__ edge_h,
                        const int*   __restrict__ edge_index,
                        const short* __restrict__ wpack,
                        const float* __restrict__ b1,
                        const float* __restrict__ b2,
                        float* __restrict__ hs_out) {
  // LDS (bytes), 24576 total -> 6 blocks/CU (LDS-wise):
  //  [0,24576)      Xs 48x256 bf16 swizzled (node_j|edge_h); dead after GEMM1
  //  [12288,24576)  H1s 48x128 bf16 swizzled (overlays Xs; written post-barrier2)
  __shared__ __align__(16) char smem[24576];
  short* Xs  = (short*)smem;
  short* H1s = (short*)(smem + 12288);

  const int tid  = threadIdx.x;
  const int blk  = blockIdx.x;
  const int bb   = blk >> 11;
  const int lane = tid & 63;
  const int wave = tid >> 6;
  const int lr   = lane & 15;
  const int lq   = lane >> 4;

  const short* W1i = wpack;
  const short* W1e = wpack + 16384;
  const short* W2p = wpack + 49152;

  // ================= front-loaded, dependency-broken prologue =============
  // (a) staging loads: w = 16B granule (0..15 node_j, 16..31 edge), rr = row%8
  const int w  = tid & 31;
  const int rr = tid >> 5;
  int idxv[6];
  if (w < 16) {
#pragma unroll
    for (int k = 0; k < 6; k++)
      idxv[k] = edge_index[blk * Kn + rr + k * 8];
  }

  // (b) node_i A-frags straight from global (only lanes lr==0 active)
  bf16x8 avk[4] = {{0}, {0}, {0}, {0}};
  if (lr == 0) {
    const float* p = node_h + (size_t)blk * Cn;
#pragma unroll
    for (int kt = 0; kt < 4; kt++) {
      float4 a0 = *reinterpret_cast<const float4*>(p + kt * 32 + lq * 8);
      float4 a1 = *reinterpret_cast<const float4*>(p + kt * 32 + lq * 8 + 4);
      union { unsigned u[4]; bf16x8 v; } q;
      q.u[0] = pk2(a0.x, a0.y); q.u[1] = pk2(a0.z, a0.w);
      q.u[2] = pk2(a1.x, a1.y); q.u[3] = pk2(a1.z, a1.w);
      avk[kt] = q.v;
    }
  }

  // (c) W1i B-frags (4) + accY row-vector MFMA (overlaps staging latency)
  f32x4 accY[2] = {};
  {
    bf16x8 bi[4];
#pragma unroll
    for (int kt = 0; kt < 4; kt++) {
      int t = kt * 8 + wave * 2;
      bi[kt] = *reinterpret_cast<const bf16x8*>(W1i + (t << 9) + lane * 8);
    }
    // j=0 tile t, j=1 tile t+1 — need both; load pairwise
#pragma unroll
    for (int kt = 0; kt < 4; kt++) {
      int t = kt * 8 + wave * 2;
      bf16x8 bj = *reinterpret_cast<const bf16x8*>(W1i + ((t + 1) << 9) + lane * 8);
      accY[0] = __builtin_amdgcn_mfma_f32_16x16x32_bf16(avk[kt], bi[kt], accY[0], 0, 0, 0);
      accY[1] = __builtin_amdgcn_mfma_f32_16x16x32_bf16(avk[kt], bj, accY[1], 0, 0, 0);
    }
  }

  // (d) staging: gather, cvt, swizzled LDS write
#pragma unroll
  for (int k = 0; k < 6; k++) {
    int r = rr + k * 8;
    const float* src = (w < 16)
        ? node_h + (size_t)(bb * Nn + idxv[k]) * Cn + w * 8
        : edge_h + ((size_t)blk * Kn + r) * Cn + (w - 16) * 8;
    float4 v0 = *reinterpret_cast<const float4*>(src);
    float4 v1 = *reinterpret_cast<const float4*>(src + 4);
    uint4 p;
    p.x = pk2(v0.x, v0.y); p.y = pk2(v0.z, v0.w);
    p.z = pk2(v1.x, v1.y); p.w = pk2(v1.z, v1.w);
    *reinterpret_cast<uint4*>(&Xs[r * 256 + ((w ^ (r & 7)) << 3)]) = p;
  }

  // (e) preload ALL GEMM1 B-frags (16 x 4 VGPR = 64 VGPR)
  bf16x8 Bf[16];
#pragma unroll
  for (int t = 0; t < 16; t++) {
    int tile = (t >> 1) * 8 + wave * 2 + (t & 1);
    Bf[t] = *reinterpret_cast<const bf16x8*>(W1e + (tile << 9) + lane * 8);
  }
  __syncthreads();   // barrier 1: Xs staged

  // ================= GEMM1: (48x256) @ W1[128:384], B in regs =============
  f32x4 acc[3][2] = {};
  {
    int sw0 = ((lq ^ (lr & 7)) << 3);
    bf16x8 a0 = *reinterpret_cast<const bf16x8*>(&Xs[(0  + lr) * 256 + sw0]);
    bf16x8 a1 = *reinterpret_cast<const bf16x8*>(&Xs[(16 + lr) * 256 + sw0]);
    bf16x8 a2 = *reinterpret_cast<const bf16x8*>(&Xs[(32 + lr) * 256 + sw0]);
#pragma unroll
    for (int kt = 0; kt < 8; kt++) {
      bf16x8 n0, n1, n2;
      if (kt < 7) {
        int sw = ((((kt + 1) * 4 + lq) ^ (lr & 7)) << 3);
        n0 = *reinterpret_cast<const bf16x8*>(&Xs[(0  + lr) * 256 + sw]);
        n1 = *reinterpret_cast<const bf16x8*>(&Xs[(16 + lr) * 256 + sw]);
        n2 = *reinterpret_cast<const bf16x8*>(&Xs[(32 + lr) * 256 + sw]);
      }
      acc[0][0] = __builtin_amdgcn_mfma_f32_16x16x32_bf16(a0, Bf[kt*2+0], acc[0][0], 0, 0, 0);
      acc[0][1] = __builtin_amdgcn_mfma_f32_16x16x32_bf16(a0, Bf[kt*2+1], acc[0][1], 0, 0, 0);
      acc[1][0] = __builtin_amdgcn_mfma_f32_16x16x32_bf16(a1, Bf[kt*2+0], acc[1][0], 0, 0, 0);
      acc[1][1] = __builtin_amdgcn_mfma_f32_16x16x32_bf16(a1, Bf[kt*2+1], acc[1][1], 0, 0, 0);
      acc[2][0] = __builtin_amdgcn_mfma_f32_16x16x32_bf16(a2, Bf[kt*2+0], acc[2][0], 0, 0, 0);
      acc[2][1] = __builtin_amdgcn_mfma_f32_16x16x32_bf16(a2, Bf[kt*2+1], acc[2][1], 0, 0, 0);
      a0 = n0; a1 = n1; a2 = n2;
    }
  }

  // preload GEMM2 B-frags (8) — latency hidden behind epilogue-1 gelu VALU
  bf16x8 B2[8];
#pragma unroll
  for (int t = 0; t < 8; t++) {
    int tile = (t >> 1) * 8 + wave * 2 + (t & 1);
    B2[t] = *reinterpret_cast<const bf16x8*>(W2p + (tile << 9) + lane * 8);
  }
  __syncthreads();   // barrier 2: all Xs reads done before H1s overlay writes

  // ---- GEMM1 epilogue: +yi +b1, gelu, bf16 -> H1s ----
#pragma unroll
  for (int j = 0; j < 2; j++) {
    int col = (wave * 2 + j) * 16 + lr;
    float yi = __shfl(accY[j][0], lr) + b1[col];
    int g = col >> 3, cl = col & 7;
#pragma unroll
    for (int mt = 0; mt < 3; mt++) {
      int r0 = mt * 16 + lq * 4;
      float g0 = gelu_f(acc[mt][j][0] + yi);
      float g1 = gelu_f(acc[mt][j][1] + yi);
      float g2 = gelu_f(acc[mt][j][2] + yi);
      float g3 = gelu_f(acc[mt][j][3] + yi);
      unsigned p01 = pk2(g0, g1), p23 = pk2(g2, g3);
      H1s[(r0 + 0) * 128 + ((g ^ ((r0 + 0) & 7)) << 3) + cl] = (short)(p01 & 0xffff);
      H1s[(r0 + 1) * 128 + ((g ^ ((r0 + 1) & 7)) << 3) + cl] = (short)(p01 >> 16);
      H1s[(r0 + 2) * 128 + ((g ^ ((r0 + 2) & 7)) << 3) + cl] = (short)(p23 & 0xffff);
      H1s[(r0 + 3) * 128 + ((g ^ ((r0 + 3) & 7)) << 3) + cl] = (short)(p23 >> 16);
    }
  }
  __syncthreads();   // barrier 3: H1s complete

  // ================= GEMM2: (48x128) @ W2, B in regs ======================
  f32x4 acc2[3][2] = {};
  {
    int sw0 = ((lq ^ (lr & 7)) << 3);
    bf16x8 a0 = *reinterpret_cast<const bf16x8*>(&H1s[(0  + lr) * 128 + sw0]);
    bf16x8 a1 = *reinterpret_cast<const bf16x8*>(&H1s[(16 + lr) * 128 + sw0]);
    bf16x8 a2 = *reinterpret_cast<const bf16x8*>(&H1s[(32 + lr) * 128 + sw0]);
#pragma unroll
    for (int kt = 0; kt < 4; kt++) {
      bf16x8 n0, n1, n2;
      if (kt < 3) {
        int sw = ((((kt + 1) * 4 + lq) ^ (lr & 7)) << 3);
        n0 = *reinterpret_cast<const bf16x8*>(&H1s[(0  + lr) * 128 + sw]);
        n1 = *reinterpret_cast<const bf16x8*>(&H1s[(16 + lr) * 128 + sw]);
        n2 = *reinterpret_cast<const bf16x8*>(&H1s[(32 + lr) * 128 + sw]);
      }
      acc2[0][0] = __builtin_amdgcn_mfma_f32_16x16x32_bf16(a0, B2[kt*2+0], acc2[0][0], 0, 0, 0);
      acc2[0][1] = __builtin_amdgcn_mfma_f32_16x16x32_bf16(a0, B2[kt*2+1], acc2[0][1], 0, 0, 0);
      acc2[1][0] = __builtin_amdgcn_mfma_f32_16x16x32_bf16(a1, B2[kt*2+0], acc2[1][0], 0, 0, 0);
      acc2[1][1] = __builtin_amdgcn_mfma_f32_16x16x32_bf16(a1, B2[kt*2+1], acc2[1][1], 0, 0, 0);
      acc2[2][0] = __builtin_amdgcn_mfma_f32_16x16x32_bf16(a2, B2[kt*2+0], acc2[2][0], 0, 0, 0);
      acc2[2][1] = __builtin_amdgcn_mfma_f32_16x16x32_bf16(a2, B2[kt*2+1], acc2[2][1], 0, 0, 0);
      a0 = n0; a1 = n1; a2 = n2;
    }
  }

  // ---- epilogue 2: gelu + column-sum over 48 edges; write hs (f32) ----
#pragma unroll
  for (int j = 0; j < 2; j++) {
    int col = (wave * 2 + j) * 16 + lr;
    float bias = b2[col];
    float s = 0.f;
#pragma unroll
    for (int mt = 0; mt < 3; mt++)
#pragma unroll
      for (int r = 0; r < 4; r++) s += gelu_f(acc2[mt][j][r] + bias);
    s += __shfl_xor(s, 16);
    s += __shfl_xor(s, 32);
    if (lq == 0) hs_out[(size_t)blk * Cn + col] = s;
  }
}

// ---------------------------------------------------------------------------
// Kernel 2 (tail, batched): 16 nodes per block.
// msg = (hs @ W3 + 48*b3)/30 ; x = nh + msg ; u = LN(x) ;
// y = nh + u@Wu + bu ; out = LN(y).  Reads hs from out buffer, overwrites.
// ---------------------------------------------------------------------------
__global__ __launch_bounds__(256, 4)
void tail_kernel(const float* __restrict__ node_h,
                 const short* __restrict__ wpack,
                 const float* __restrict__ b3,
                 const float* __restrict__ bu,
                 const float* __restrict__ ln_g,
                 const float* __restrict__ ln_b,
                 float* __restrict__ out) {
  __shared__ __align__(16) char sm2[24832];
  short* hsB = (short*)sm2;
  float* nhr = (float*)(sm2 + 4096);
  float* xs  = (float*)(sm2 + 12288);
  short* usB = (short*)(sm2 + 20736);

  const int tid  = threadIdx.x;
  const int lane = tid & 63;
  const int wave = tid >> 6;
  const int lr   = lane & 15;
  const int lq   = lane >> 4;
  const int n0   = blockIdx.x * G2;

  const short* W3p = wpack + 65536;
  const short* Wup = wpack + 81920;

  {
    int row = tid >> 4, seg = tid & 15;
    const float* p = node_h + (size_t)(n0 + row) * Cn + seg * 8;
    float4 a0 = *reinterpret_cast<const float4*>(p);
    float4 a1 = *reinterpret_cast<const float4*>(p + 4);
    *reinterpret_cast<float4*>(&nhr[row * 128 + seg * 8])     = a0;
    *reinterpret_cast<float4*>(&nhr[row * 128 + seg * 8 + 4]) = a1;
    const float* q = out + (size_t)(n0 + row) * Cn + seg * 8;  // hs scratch
    float4 c0 = *reinterpret_cast<const float4*>(q);
    float4 c1 = *reinterpret_cast<const float4*>(q + 4);
    uint4 pk;
    pk.x = pk2(c0.x, c0.y); pk.y = pk2(c0.z, c0.w);
    pk.z = pk2(c1.x, c1.y); pk.w = pk2(c1.z, c1.w);
    *reinterpret_cast<uint4*>(&hsB[row * 128 + ((seg ^ (row & 7)) << 3)]) = pk;
  }
  __syncthreads();

  f32x4 am[2] = {};
#pragma unroll
  for (int kt = 0; kt < 4; kt++) {
    bf16x8 av = *reinterpret_cast<const bf16x8*>(&hsB[lr * 128 + (((kt * 4 + lq) ^ (lr & 7)) << 3)]);
    bf16x8 bv0 = *reinterpret_cast<const bf16x8*>(W3p + ((kt * 8 + wave * 2 + 0) << 9) + lane * 8);
    bf16x8 bv1 = *reinterpret_cast<const bf16x8*>(W3p + ((kt * 8 + wave * 2 + 1) << 9) + lane * 8);
    am[0] = __builtin_amdgcn_mfma_f32_16x16x32_bf16(av, bv0, am[0], 0, 0, 0);
    am[1] = __builtin_amdgcn_mfma_f32_16x16x32_bf16(av, bv1, am[1], 0, 0, 0);
  }
#pragma unroll
  for (int j = 0; j < 2; j++) {
    int col = (wave * 2 + j) * 16 + lr;
    float bb = 48.0f * b3[col];
#pragma unroll
    for (int r = 0; r < 4; r++) {
      int row = lq * 4 + r;
      xs[row * 132 + col] = nhr[row * 128 + col] + (am[j][r] + bb) * (1.0f / 30.0f);
    }
  }
  __syncthreads();

  const float lg1 = ln_g[lane],      lb1v = ln_b[lane];
  const float lg2 = ln_g[lane + 64], lb2v = ln_b[lane + 64];
#pragma unroll
  for (int s = 0; s < 4; s++) {
    int row = wave * 4 + s;
    float v1 = xs[row * 132 + lane];
    float v2 = xs[row * 132 + lane + 64];
    float s1 = v1 + v2, s2 = v1 * v1 + v2 * v2;
#pragma unroll
    for (int off = 32; off >= 1; off >>= 1) {
      s1 += __shfl_xor(s1, off);
      s2 += __shfl_xor(s2, off);
    }
    float mu = s1 * (1.f / 128.f);
    float var = s2 * (1.f / 128.f) - mu * mu;
    float rstd = rsqrtf(var + 1e-5f);
    unsigned u12 = pk2((v1 - mu) * rstd * lg1 + lb1v,
                       (v2 - mu) * rstd * lg2 + lb2v);
    int sw = (row & 7);
    usB[row * 128 + (((lane >> 3) ^ sw) << 3) + (lane & 7)]       = (short)(u12 & 0xffff);
    usB[row * 128 + ((((lane >> 3) + 8) ^ sw) << 3) + (lane & 7)] = (short)(u12 >> 16);
  }
  __syncthreads();

  f32x4 au[2] = {};
#pragma unroll
  for (int kt = 0; kt < 4; kt++) {
    bf16x8 av = *reinterpret_cast<const bf16x8*>(&usB[lr * 128 + (((kt * 4 + lq) ^ (lr & 7)) << 3)]);
    bf16x8 bv0 = *reinterpret_cast<const bf16x8*>(Wup + ((kt * 8 + wave * 2 + 0) << 9) + lane * 8);
    bf16x8 bv1 = *reinterpret_cast<const bf16x8*>(Wup + ((kt * 8 + wave * 2 + 1) << 9) + lane * 8);
    au[0] = __builtin_amdgcn_mfma_f32_16x16x32_bf16(av, bv0, au[0], 0, 0, 0);
    au[1] = __builtin_amdgcn_mfma_f32_16x16x32_bf16(av, bv1, au[1], 0, 0, 0);
  }
  __syncthreads();
#pragma unroll
  for (int j = 0; j < 2; j++) {
    int col = (wave * 2 + j) * 16 + lr;
    float bb = bu[col];
#pragma unroll
    for (int r = 0; r < 4; r++) {
      int row = lq * 4 + r;
      xs[row * 132 + col] = nhr[row * 128 + col] + au[j][r] + bb;
    }
  }
  __syncthreads();

#pragma unroll
  for (int s = 0; s < 4; s++) {
    int row = wave * 4 + s;
    float v1 = xs[row * 132 + lane];
    float v2 = xs[row * 132 + lane + 64];
    float s1 = v1 + v2, s2 = v1 * v1 + v2 * v2;
#pragma unroll
    for (int off = 32; off >= 1; off >>= 1) {
      s1 += __shfl_xor(s1, off);
      s2 += __shfl_xor(s2, off);
    }
    float mu = s1 * (1.f / 128.f);
    float var = s2 * (1.f / 128.f) - mu * mu;
    float rstd = rsqrtf(var + 1e-5f);
    out[(size_t)(n0 + row) * Cn + lane]      = (v1 - mu) * rstd * lg1 + lb1v;
    out[(size_t)(n0 + row) * Cn + lane + 64] = (v2 - mu) * rstd * lg2 + lb2v;
  }
}

extern "C" void kernel_launch(void* const* d_in, const int* in_sizes, int n_in,
                              void* d_out, int out_size, void* d_ws, size_t ws_size,
                              hipStream_t stream) {
  const float* node_h     = (const float*)d_in[0];
  const float* edge_h     = (const float*)d_in[1];
  const int*   edge_index = (const int*)  d_in[2];
  const float* W1 = (const float*)d_in[3];
  const float* b1 = (const float*)d_in[4];
  const float* W2 = (const float*)d_in[5];
  const float* b2 = (const float*)d_in[6];
  const float* W3 = (const float*)d_in[7];
  const float* b3 = (const float*)d_in[8];
  const float* Wu = (const float*)d_in[9];
  const float* bu = (const float*)d_in[10];
  const float* ln_g = (const float*)d_in[11];
  const float* ln_b = (const float*)d_in[12];
  float* out   = (float*)d_out;
  short* wpack = (short*)d_ws;   // 192 KiB

  pack_weights<<<48, 256, 0, stream>>>(W1, W2, W3, Wu, wpack);
  node_update_kernel<<<Bn * Nn, 256, 0, stream>>>(
      node_h, edge_h, edge_index, wpack, b1, b2, out);
  tail_kernel<<<(Bn * Nn) / G2, 256, 0, stream>>>(
      node_h, wpack, b3, bu, ln_g, ln_b, out);
}

// Round 7
// 208.523 us; speedup vs baseline: 1.0148x; 1.0148x over previous
//
#include <hip/hip_runtime.h>
#include <hip/hip_bf16.h>
#include <math.h>

// Problem constants
#define Bn   2
#define Nn   2048
#define Kn   48
#define Cn   128
#define G2   16     // nodes per block in the tail kernel

// LDS granule swizzle: rows r, r+4, r+8, r+12 (one epilogue write inst) get
// 4 DISTINCT granule offsets (kills the 2-way*2 write serialization the old
// row&7 swizzle had), while A-frag b128 reads keep exactly 8 lanes/bank-quad.
#define SIG(r) ((((r) ^ ((r) >> 2))) & 7)

typedef short bf16x8 __attribute__((ext_vector_type(8)));
typedef float f32x4  __attribute__((ext_vector_type(4)));

#if __has_builtin(__builtin_amdgcn_cvt_pk_bf16_f32)
#define HAS_PK 1
#endif

__device__ __forceinline__ short f2bf(float f) {
  union { float f; unsigned u; } v; v.f = f;
  unsigned r = v.u + 0x7fffu + ((v.u >> 16) & 1u);
  return (short)(r >> 16);
}

__device__ __forceinline__ unsigned pk2(float a, float b) {
#ifdef HAS_PK
  auto p = __builtin_amdgcn_cvt_pk_bf16_f32(a, b);
  return __builtin_bit_cast(unsigned, p);
#else
  return (unsigned)(unsigned short)f2bf(a) | ((unsigned)(unsigned short)f2bf(b) << 16);
#endif
}

// tanh-GELU with exp2-folded constants; |err| vs erf-gelu ~3e-4.
__device__ __forceinline__ float gelu_f(float x) {
  float z = x * (-2.3021991f - 0.10294200f * x * x);
  float e = __builtin_amdgcn_exp2f(z);
  return x * __builtin_amdgcn_rcpf(1.0f + e);
}

// ---------------------------------------------------------------------------
// Pack weights into bf16 MFMA B-fragment tiles (512 shorts each; lane l holds
// 8 bf16 = W[kt*32 + (l>>4)*8 + j][nt*16 + (l&15)]).
// ws (shorts): W1i [0,16384) | W1e [16384,49152) | W2 [49152,65536)
//              W3 [65536,81920) | Wu [81920,98304)
// ---------------------------------------------------------------------------
__global__ void pack_weights(const float* __restrict__ W1,
                             const float* __restrict__ W2,
                             const float* __restrict__ W3,
                             const float* __restrict__ Wu,
                             short* __restrict__ ws) {
  int tid = blockIdx.x * blockDim.x + threadIdx.x;
  if (tid >= 192 * 64) return;
  int lane = tid & 63;
  int tile = tid >> 6;
  const float* W; short* dst;
  if (tile < 32)       { W = W1;         dst = ws; }
  else if (tile < 96)  { W = W1 + 16384; dst = ws + 16384; tile -= 32; }
  else if (tile < 128) { W = W2;         dst = ws + 49152; tile -= 96; }
  else if (tile < 160) { W = W3;         dst = ws + 65536; tile -= 128; }
  else                 { W = Wu;         dst = ws + 81920; tile -= 160; }
  int kt = tile >> 3, nt = tile & 7;
  int n  = nt * 16 + (lane & 15);
  int k0 = kt * 32 + (lane >> 4) * 8;
  union { short s[8]; bf16x8 v; } u8;
#pragma unroll
  for (int j = 0; j < 8; j++) u8.s[j] = f2bf(W[(k0 + j) * 128 + n]);
  *reinterpret_cast<bf16x8*>(dst + (tile << 9) + lane * 8) = u8.v;
}

// ---------------------------------------------------------------------------
// Kernel 1: per-node edge MLP. One block per node; 256 thr = 4 waves; wave w
// owns cols [w*32,w*32+32). In-loop B loads (reg-lean), phase-0 elimination,
// SIG swizzle. 3 barriers.
// NOTE (R6 bug): MFMA must execute UNIFORMLY — only the A-fragment LOADS may
// be predicated (inactive lanes keep zero fragments). MFMA reads A from all
// 64 lanes' registers regardless of EXEC.
// Ends writing hs[node][128] (f32 col-sums of gelu(h2)) into the out buffer.
// ---------------------------------------------------------------------------
__global__ __launch_bounds__(256, 6)
void node_update_kernel(const float* __restrict__ node_h,
                        const float* __restrict__ edge_h,
                        const int*   __restrict__ edge_index,
                        const short* __restrict__ wpack,
                        const float* __restrict__ b1,
                        const float* __restrict__ b2,
                        float* __restrict__ hs_out) {
  // LDS (bytes), 24576 total -> 6 blocks/CU:
  //  [0,24576)      Xs 48x256 bf16 swizzled (node_j|edge_h); dead after GEMM1
  //  [12288,24576)  H1s 48x128 bf16 swizzled (overlays Xs; written post-barrier2)
  __shared__ __align__(16) char smem[24576];
  short* Xs  = (short*)smem;
  short* H1s = (short*)(smem + 12288);

  const int tid  = threadIdx.x;
  const int blk  = blockIdx.x;
  const int bb   = blk >> 11;
  const int lane = tid & 63;
  const int wave = tid >> 6;
  const int lr   = lane & 15;
  const int lq   = lane >> 4;

  const short* W1i = wpack;
  const short* W1e = wpack + 16384;
  const short* W2p = wpack + 49152;

  // ---- prologue: issue idx loads first (staging address dependency) ----
  const int w  = tid & 31;   // 16B granule (0..15 node_j, 16..31 edge)
  const int rr = tid >> 5;   // row % 8
  int idxv[6];
  if (w < 16) {
#pragma unroll
    for (int k = 0; k < 6; k++)
      idxv[k] = edge_index[blk * Kn + rr + k * 8];
  }

  // ---- node_i row-vector MFMA: loads predicated, MFMA uniform ----
  f32x4 accY[2] = {};
  {
    bf16x8 avk[4] = {{0}, {0}, {0}, {0}};
    if (lr == 0) {
      const float* p = node_h + (size_t)blk * Cn;
#pragma unroll
      for (int kt = 0; kt < 4; kt++) {
        float4 a0 = *reinterpret_cast<const float4*>(p + kt * 32 + lq * 8);
        float4 a1 = *reinterpret_cast<const float4*>(p + kt * 32 + lq * 8 + 4);
        union { unsigned u[4]; bf16x8 v; } q;
        q.u[0] = pk2(a0.x, a0.y); q.u[1] = pk2(a0.z, a0.w);
        q.u[2] = pk2(a1.x, a1.y); q.u[3] = pk2(a1.z, a1.w);
        avk[kt] = q.v;
      }
    }
#pragma unroll
    for (int kt = 0; kt < 4; kt++) {
      bf16x8 bv0 = *reinterpret_cast<const bf16x8*>(W1i + ((kt * 8 + wave * 2 + 0) << 9) + lane * 8);
      bf16x8 bv1 = *reinterpret_cast<const bf16x8*>(W1i + ((kt * 8 + wave * 2 + 1) << 9) + lane * 8);
      accY[0] = __builtin_amdgcn_mfma_f32_16x16x32_bf16(avk[kt], bv0, accY[0], 0, 0, 0);
      accY[1] = __builtin_amdgcn_mfma_f32_16x16x32_bf16(avk[kt], bv1, accY[1], 0, 0, 0);
    }
  }

  // ---- stage X = [node_j | edge_h] bf16, SIG-swizzled ----
#pragma unroll
  for (int k = 0; k < 6; k++) {
    int r = rr + k * 8;
    const float* src = (w < 16)
        ? node_h + (size_t)(bb * Nn + idxv[k]) * Cn + w * 8
        : edge_h + ((size_t)blk * Kn + r) * Cn + (w - 16) * 8;
    float4 v0 = *reinterpret_cast<const float4*>(src);
    float4 v1 = *reinterpret_cast<const float4*>(src + 4);
    uint4 p;
    p.x = pk2(v0.x, v0.y); p.y = pk2(v0.z, v0.w);
    p.z = pk2(v1.x, v1.y); p.w = pk2(v1.z, v1.w);
    *reinterpret_cast<uint4*>(&Xs[r * 256 + ((w ^ SIG(r)) << 3)]) = p;
  }
  __syncthreads();   // barrier 1: Xs staged

  // ---- GEMM1: (48x256) @ W1[128:384], B loads in-loop (reg-lean) ----
  // row sets: a0 rows lr (SIG=s0), a1 rows 16+lr (SIG=s0^4), a2 rows 32+lr (SIG=s0)
  const int s0 = SIG(lr);
  f32x4 acc[3][2] = {};
#pragma unroll
  for (int kt = 0; kt < 8; kt++) {
    bf16x8 bf0 = *reinterpret_cast<const bf16x8*>(W1e + ((kt * 8 + wave * 2 + 0) << 9) + lane * 8);
    bf16x8 bf1 = *reinterpret_cast<const bf16x8*>(W1e + ((kt * 8 + wave * 2 + 1) << 9) + lane * 8);
    int swA = (((kt * 4 + lq) ^ s0) << 3);
    int swB = swA ^ (4 << 3);
    bf16x8 a0 = *reinterpret_cast<const bf16x8*>(&Xs[(0  + lr) * 256 + swA]);
    bf16x8 a1 = *reinterpret_cast<const bf16x8*>(&Xs[(16 + lr) * 256 + swB]);
    bf16x8 a2 = *reinterpret_cast<const bf16x8*>(&Xs[(32 + lr) * 256 + swA]);
    acc[0][0] = __builtin_amdgcn_mfma_f32_16x16x32_bf16(a0, bf0, acc[0][0], 0, 0, 0);
    acc[0][1] = __builtin_amdgcn_mfma_f32_16x16x32_bf16(a0, bf1, acc[0][1], 0, 0, 0);
    acc[1][0] = __builtin_amdgcn_mfma_f32_16x16x32_bf16(a1, bf0, acc[1][0], 0, 0, 0);
    acc[1][1] = __builtin_amdgcn_mfma_f32_16x16x32_bf16(a1, bf1, acc[1][1], 0, 0, 0);
    acc[2][0] = __builtin_amdgcn_mfma_f32_16x16x32_bf16(a2, bf0, acc[2][0], 0, 0, 0);
    acc[2][1] = __builtin_amdgcn_mfma_f32_16x16x32_bf16(a2, bf1, acc[2][1], 0, 0, 0);
  }
  __syncthreads();   // barrier 2: all Xs reads done before H1s overlay writes

  // ---- GEMM1 epilogue: +yi +b1, gelu, bf16 -> H1s (SIG-swizzled writes) ----
  // SIG(mt*16 + lq*4 + i) = ((lq*5)&7) ^ i ^ ((mt&1)<<2)
  const int s5 = (lq * 5) & 7;
#pragma unroll
  for (int j = 0; j < 2; j++) {
    int col = (wave * 2 + j) * 16 + lr;
    float yi = __shfl(accY[j][0], lr) + b1[col];
    int cl = col & 7;
#pragma unroll
    for (int mt = 0; mt < 3; mt++) {
      int r0 = mt * 16 + lq * 4;
      int gs = (col >> 3) ^ s5 ^ ((mt & 1) << 2);
      float g0 = gelu_f(acc[mt][j][0] + yi);
      float g1 = gelu_f(acc[mt][j][1] + yi);
      float g2 = gelu_f(acc[mt][j][2] + yi);
      float g3 = gelu_f(acc[mt][j][3] + yi);
      unsigned p01 = pk2(g0, g1), p23 = pk2(g2, g3);
      H1s[(r0 + 0) * 128 + ((gs ^ 0) << 3) + cl] = (short)(p01 & 0xffff);
      H1s[(r0 + 1) * 128 + ((gs ^ 1) << 3) + cl] = (short)(p01 >> 16);
      H1s[(r0 + 2) * 128 + ((gs ^ 2) << 3) + cl] = (short)(p23 & 0xffff);
      H1s[(r0 + 3) * 128 + ((gs ^ 3) << 3) + cl] = (short)(p23 >> 16);
    }
  }
  __syncthreads();   // barrier 3: H1s complete

  // ---- GEMM2: (48x128) @ W2, fused gelu + column-sum; write hs (f32) ----
  f32x4 acc2[3][2] = {};
#pragma unroll
  for (int kt = 0; kt < 4; kt++) {
    bf16x8 bf0 = *reinterpret_cast<const bf16x8*>(W2p + ((kt * 8 + wave * 2 + 0) << 9) + lane * 8);
    bf16x8 bf1 = *reinterpret_cast<const bf16x8*>(W2p + ((kt * 8 + wave * 2 + 1) << 9) + lane * 8);
    int swA = (((kt * 4 + lq) ^ s0) << 3);
    int swB = swA ^ (4 << 3);
    bf16x8 a0 = *reinterpret_cast<const bf16x8*>(&H1s[(0  + lr) * 128 + swA]);
    bf16x8 a1 = *reinterpret_cast<const bf16x8*>(&H1s[(16 + lr) * 128 + swB]);
    bf16x8 a2 = *reinterpret_cast<const bf16x8*>(&H1s[(32 + lr) * 128 + swA]);
    acc2[0][0] = __builtin_amdgcn_mfma_f32_16x16x32_bf16(a0, bf0, acc2[0][0], 0, 0, 0);
    acc2[0][1] = __builtin_amdgcn_mfma_f32_16x16x32_bf16(a0, bf1, acc2[0][1], 0, 0, 0);
    acc2[1][0] = __builtin_amdgcn_mfma_f32_16x16x32_bf16(a1, bf0, acc2[1][0], 0, 0, 0);
    acc2[1][1] = __builtin_amdgcn_mfma_f32_16x16x32_bf16(a1, bf1, acc2[1][1], 0, 0, 0);
    acc2[2][0] = __builtin_amdgcn_mfma_f32_16x16x32_bf16(a2, bf0, acc2[2][0], 0, 0, 0);
    acc2[2][1] = __builtin_amdgcn_mfma_f32_16x16x32_bf16(a2, bf1, acc2[2][1], 0, 0, 0);
  }
#pragma unroll
  for (int j = 0; j < 2; j++) {
    int col = (wave * 2 + j) * 16 + lr;
    float bias = b2[col];
    float s = 0.f;
#pragma unroll
    for (int mt = 0; mt < 3; mt++)
#pragma unroll
      for (int r = 0; r < 4; r++) s += gelu_f(acc2[mt][j][r] + bias);
    s += __shfl_xor(s, 16);
    s += __shfl_xor(s, 32);
    if (lq == 0) hs_out[(size_t)blk * Cn + col] = s;
  }
}

// ---------------------------------------------------------------------------
// Kernel 2 (tail, batched): 16 nodes per block.
// msg = (hs @ W3 + 48*b3)/30 ; x = nh + msg ; u = LN(x) ;
// y = nh + u@Wu + bu ; out = LN(y).  Reads hs from out buffer, overwrites.
// ---------------------------------------------------------------------------
__global__ __launch_bounds__(256, 4)
void tail_kernel(const float* __restrict__ node_h,
                 const short* __restrict__ wpack,
                 const float* __restrict__ b3,
                 const float* __restrict__ bu,
                 const float* __restrict__ ln_g,
                 const float* __restrict__ ln_b,
                 float* __restrict__ out) {
  __shared__ __align__(16) char sm2[24832];
  short* hsB = (short*)sm2;
  float* nhr = (float*)(sm2 + 4096);
  float* xs  = (float*)(sm2 + 12288);
  short* usB = (short*)(sm2 + 20736);

  const int tid  = threadIdx.x;
  const int lane = tid & 63;
  const int wave = tid >> 6;
  const int lr   = lane & 15;
  const int lq   = lane >> 4;
  const int n0   = blockIdx.x * G2;

  const short* W3p = wpack + 65536;
  const short* Wup = wpack + 81920;

  {
    int row = tid >> 4, seg = tid & 15;
    const float* p = node_h + (size_t)(n0 + row) * Cn + seg * 8;
    float4 a0 = *reinterpret_cast<const float4*>(p);
    float4 a1 = *reinterpret_cast<const float4*>(p + 4);
    *reinterpret_cast<float4*>(&nhr[row * 128 + seg * 8])     = a0;
    *reinterpret_cast<float4*>(&nhr[row * 128 + seg * 8 + 4]) = a1;
    const float* q = out + (size_t)(n0 + row) * Cn + seg * 8;  // hs scratch
    float4 c0 = *reinterpret_cast<const float4*>(q);
    float4 c1 = *reinterpret_cast<const float4*>(q + 4);
    uint4 pk;
    pk.x = pk2(c0.x, c0.y); pk.y = pk2(c0.z, c0.w);
    pk.z = pk2(c1.x, c1.y); pk.w = pk2(c1.z, c1.w);
    *reinterpret_cast<uint4*>(&hsB[row * 128 + ((seg ^ (row & 7)) << 3)]) = pk;
  }
  __syncthreads();

  f32x4 am[2] = {};
#pragma unroll
  for (int kt = 0; kt < 4; kt++) {
    bf16x8 av = *reinterpret_cast<const bf16x8*>(&hsB[lr * 128 + (((kt * 4 + lq) ^ (lr & 7)) << 3)]);
    bf16x8 bv0 = *reinterpret_cast<const bf16x8*>(W3p + ((kt * 8 + wave * 2 + 0) << 9) + lane * 8);
    bf16x8 bv1 = *reinterpret_cast<const bf16x8*>(W3p + ((kt * 8 + wave * 2 + 1) << 9) + lane * 8);
    am[0] = __builtin_amdgcn_mfma_f32_16x16x32_bf16(av, bv0, am[0], 0, 0, 0);
    am[1] = __builtin_amdgcn_mfma_f32_16x16x32_bf16(av, bv1, am[1], 0, 0, 0);
  }
#pragma unroll
  for (int j = 0; j < 2; j++) {
    int col = (wave * 2 + j) * 16 + lr;
    float bb = 48.0f * b3[col];
#pragma unroll
    for (int r = 0; r < 4; r++) {
      int row = lq * 4 + r;
      xs[row * 132 + col] = nhr[row * 128 + col] + (am[j][r] + bb) * (1.0f / 30.0f);
    }
  }
  __syncthreads();

  const float lg1 = ln_g[lane],      lb1v = ln_b[lane];
  const float lg2 = ln_g[lane + 64], lb2v = ln_b[lane + 64];
#pragma unroll
  for (int s = 0; s < 4; s++) {
    int row = wave * 4 + s;
    float v1 = xs[row * 132 + lane];
    float v2 = xs[row * 132 + lane + 64];
    float s1 = v1 + v2, s2 = v1 * v1 + v2 * v2;
#pragma unroll
    for (int off = 32; off >= 1; off >>= 1) {
      s1 += __shfl_xor(s1, off);
      s2 += __shfl_xor(s2, off);
    }
    float mu = s1 * (1.f / 128.f);
    float var = s2 * (1.f / 128.f) - mu * mu;
    float rstd = rsqrtf(var + 1e-5f);
    unsigned u12 = pk2((v1 - mu) * rstd * lg1 + lb1v,
                       (v2 - mu) * rstd * lg2 + lb2v);
    int sw = (row & 7);
    usB[row * 128 + (((lane >> 3) ^ sw) << 3) + (lane & 7)]       = (short)(u12 & 0xffff);
    usB[row * 128 + ((((lane >> 3) + 8) ^ sw) << 3) + (lane & 7)] = (short)(u12 >> 16);
  }
  __syncthreads();

  f32x4 au[2] = {};
#pragma unroll
  for (int kt = 0; kt < 4; kt++) {
    bf16x8 av = *reinterpret_cast<const bf16x8*>(&usB[lr * 128 + (((kt * 4 + lq) ^ (lr & 7)) << 3)]);
    bf16x8 bv0 = *reinterpret_cast<const bf16x8*>(Wup + ((kt * 8 + wave * 2 + 0) << 9) + lane * 8);
    bf16x8 bv1 = *reinterpret_cast<const bf16x8*>(Wup + ((kt * 8 + wave * 2 + 1) << 9) + lane * 8);
    au[0] = __builtin_amdgcn_mfma_f32_16x16x32_bf16(av, bv0, au[0], 0, 0, 0);
    au[1] = __builtin_amdgcn_mfma_f32_16x16x32_bf16(av, bv1, au[1], 0, 0, 0);
  }
  __syncthreads();
#pragma unroll
  for (int j = 0; j < 2; j++) {
    int col = (wave * 2 + j) * 16 + lr;
    float bb = bu[col];
#pragma unroll
    for (int r = 0; r < 4; r++) {
      int row = lq * 4 + r;
      xs[row * 132 + col] = nhr[row * 128 + col] + au[j][r] + bb;
    }
  }
  __syncthreads();

#pragma unroll
  for (int s = 0; s < 4; s++) {
    int row = wave * 4 + s;
    float v1 = xs[row * 132 + lane];
    float v2 = xs[row * 132 + lane + 64];
    float s1 = v1 + v2, s2 = v1 * v1 + v2 * v2;
#pragma unroll
    for (int off = 32; off >= 1; off >>= 1) {
      s1 += __shfl_xor(s1, off);
      s2 += __shfl_xor(s2, off);
    }
    float mu = s1 * (1.f / 128.f);
    float var = s2 * (1.f / 128.f) - mu * mu;
    float rstd = rsqrtf(var + 1e-5f);
    out[(size_t)(n0 + row) * Cn + lane]      = (v1 - mu) * rstd * lg1 + lb1v;
    out[(size_t)(n0 + row) * Cn + lane + 64] = (v2 - mu) * rstd * lg2 + lb2v;
  }
}

extern "C" void kernel_launch(void* const* d_in, const int* in_sizes, int n_in,
                              void* d_out, int out_size, void* d_ws, size_t ws_size,
                              hipStream_t stream) {
  const float* node_h     = (const float*)d_in[0];
  const float* edge_h     = (const float*)d_in[1];
  const int*   edge_index = (const int*)  d_in[2];
  const float* W1 = (const float*)d_in[3];
  const float* b1 = (const float*)d_in[4];
  const float* W2 = (const float*)d_in[5];
  const float* b2 = (const float*)d_in[6];
  const float* W3 = (const float*)d_in[7];
  const float* b3 = (const float*)d_in[8];
  const float* Wu = (const float*)d_in[9];
  const float* bu = (const float*)d_in[10];
  const float* ln_g = (const float*)d_in[11];
  const float* ln_b = (const float*)d_in[12];
  float* out   = (float*)d_out;
  short* wpack = (short*)d_ws;   // 192 KiB

  pack_weights<<<48, 256, 0, stream>>>(W1, W2, W3, Wu, wpack);
  node_update_kernel<<<Bn * Nn, 256, 0, stream>>>(
      node_h, edge_h, edge_index, wpack, b1, b2, out);
  tail_kernel<<<(Bn * Nn) / G2, 256, 0, stream>>>(
      node_h, wpack, b3, bu, ln_g, ln_b, out);
}